// Round 2
// baseline (22434.653 us; speedup 1.0000x reference)
//
#include <hip/hip_runtime.h>

// ---- problem constants ----
#define NB 8192      // batch rows
#define NM 1024      // image dim
#define NK 2048      // dictionary size
#define MAX_T 116    // iteration slots (expected ~101 live)
#define STEPF (0.1f * (2.0f / (8192.0f * 1024.0f)))
#define LMB 1e-12f

typedef unsigned short ushort_t;
using bf16x8 = __attribute__((ext_vector_type(8))) short;
using f32x4  = __attribute__((ext_vector_type(4))) float;

struct Ctrl { double nd; double dd; int flag; int last; };

__device__ __forceinline__ ushort_t f2bf(float f) {
  union { float f; unsigned u; } v; v.f = f;
  unsigned r = (v.u + 0x7FFFu + ((v.u >> 16) & 1u)) >> 16;  // RNE
  return (ushort_t)r;
}

__device__ __forceinline__ void gload_lds16(const void* g, void* l) {
  __builtin_amdgcn_global_load_lds(
      (const __attribute__((address_space(1))) unsigned int*)g,
      (__attribute__((address_space(3))) unsigned int*)l, 16, 0, 0);
}

// C = Aop(row-major [rows][KK]) * Bop^T (Bop row-major [cols][KK]); 128x128 tile,
// BK=64, 4 waves, each wave 64x64 via 4x4 frags of mfma_f32_16x16x32_bf16.
// MODE 0: write bf16 C (outbf, ld=outld)
// MODE 1: write f32 C (outf, ld=outld)
// MODE 2: ISTA update epilogue: r_new = shrink(r - STEP*(C - G0)); writes Rst f32,
//         rbn bf16, accumulates f64 sums of (dr)^2 and r_old^2 into ctrl.
template<int MODE>
__global__ __launch_bounds__(256)
void gemm_bt(const ushort_t* __restrict__ Aop, const ushort_t* __restrict__ Bop,
             int KK, int njb, int outld,
             float* __restrict__ outf, ushort_t* __restrict__ outbf,
             const float* __restrict__ G0, float* __restrict__ Rst,
             ushort_t* __restrict__ rbn, Ctrl* __restrict__ ctrl)
{
  if constexpr (MODE == 2) { if (ctrl->flag) return; }

  const int tid = threadIdx.x;
  const int w = tid >> 6, l = tid & 63;
  const int wm = w >> 1, wn = w & 1;
  const int bi = blockIdx.x / njb, bj = blockIdx.x % njb;
  const int i0 = bi * 128, j0 = bj * 128;
  const int l15 = l & 15, l16 = l >> 4;
  const int lr = l >> 3;          // staging row-within-8
  const int lc = (l & 7) * 8;     // staging col (elements)

  __shared__ __align__(128) ushort_t As[128 * 64];
  __shared__ __align__(128) ushort_t Bs[128 * 64];
  __shared__ double red[8];

  f32x4 acc[4][4];
#pragma unroll
  for (int m = 0; m < 4; ++m)
#pragma unroll
    for (int n = 0; n < 4; ++n)
      acc[m][n] = (f32x4){0.f, 0.f, 0.f, 0.f};

  for (int k0 = 0; k0 < KK; k0 += 64) {
    // stage 128x64 bf16 tiles of A and B^T via async global->LDS (16B/lane)
#pragma unroll
    for (int c = 0; c < 4; ++c) {
      const int rr = c * 32 + w * 8 + lr;
      const ushort_t* ga = Aop + ((size_t)(i0 + rr) * (size_t)KK + k0 + lc);
      const ushort_t* gb = Bop + ((size_t)(j0 + rr) * (size_t)KK + k0 + lc);
      const int base = w * 512 + c * 2048;  // wave-uniform LDS element base
      gload_lds16(ga, &As[base]);
      gload_lds16(gb, &Bs[base]);
    }
    __syncthreads();
#pragma unroll
    for (int ks = 0; ks < 2; ++ks) {
      bf16x8 af[4], bfr[4];
#pragma unroll
      for (int m = 0; m < 4; ++m)
        af[m] = *(const bf16x8*)&As[(wm * 64 + m * 16 + l15) * 64 + ks * 32 + l16 * 8];
#pragma unroll
      for (int n = 0; n < 4; ++n)
        bfr[n] = *(const bf16x8*)&Bs[(wn * 64 + n * 16 + l15) * 64 + ks * 32 + l16 * 8];
#pragma unroll
      for (int m = 0; m < 4; ++m)
#pragma unroll
        for (int n = 0; n < 4; ++n)
          acc[m][n] = __builtin_amdgcn_mfma_f32_16x16x32_bf16(af[m], bfr[n], acc[m][n], 0, 0, 0);
    }
    __syncthreads();
  }

  // epilogue: C/D layout col = lane&15, row = (lane>>4)*4 + reg
  if constexpr (MODE == 2) {
    double sd = 0.0, sr = 0.0;
#pragma unroll
    for (int m = 0; m < 4; ++m) {
#pragma unroll
      for (int n = 0; n < 4; ++n) {
        const int gr0 = i0 + wm * 64 + m * 16 + l16 * 4;
        const int gc  = j0 + wn * 64 + n * 16 + l15;
#pragma unroll
        for (int q4 = 0; q4 < 4; ++q4) {
          const size_t idx = (size_t)(gr0 + q4) * (size_t)outld + gc;
          const float qv = acc[m][n][q4];
          const float g0 = G0[idx];
          const float ro = Rst[idx];
          const float x  = ro - STEPF * (qv - g0);
          const float rv = fmaxf(x - LMB, 0.f) - fmaxf(-x - LMB, 0.f);
          Rst[idx] = rv;
          rbn[idx] = f2bf(rv);
          const float dlt = rv - ro;
          sd += (double)dlt * (double)dlt;
          sr += (double)ro * (double)ro;
        }
      }
    }
#pragma unroll
    for (int off = 32; off > 0; off >>= 1) {
      sd += __shfl_down(sd, off, 64);
      sr += __shfl_down(sr, off, 64);
    }
    if (l == 0) { red[w] = sd; red[4 + w] = sr; }
    __syncthreads();
    if (tid == 0) {
      atomicAdd(&ctrl->nd, red[0] + red[1] + red[2] + red[3]);
      atomicAdd(&ctrl->dd, red[4] + red[5] + red[6] + red[7]);
    }
  } else if constexpr (MODE == 1) {
#pragma unroll
    for (int m = 0; m < 4; ++m)
#pragma unroll
      for (int n = 0; n < 4; ++n) {
        const int gr0 = i0 + wm * 64 + m * 16 + l16 * 4;
        const int gc  = j0 + wn * 64 + n * 16 + l15;
#pragma unroll
        for (int q4 = 0; q4 < 4; ++q4)
          outf[(size_t)(gr0 + q4) * (size_t)outld + gc] = acc[m][n][q4];
      }
  } else {
#pragma unroll
    for (int m = 0; m < 4; ++m)
#pragma unroll
      for (int n = 0; n < 4; ++n) {
        const int gr0 = i0 + wm * 64 + m * 16 + l16 * 4;
        const int gc  = j0 + wn * 64 + n * 16 + l15;
#pragma unroll
        for (int q4 = 0; q4 < 4; ++q4)
          outbf[(size_t)(gr0 + q4) * (size_t)outld + gc] = f2bf(acc[m][n][q4]);
      }
  }
}

__global__ void conv_img_k(const float* __restrict__ src, ushort_t* __restrict__ dst) {
  int i = blockIdx.x * blockDim.x + threadIdx.x;
  const int stride = gridDim.x * blockDim.x;
  const int n4 = (NB * NM) / 4;
  for (; i < n4; i += stride) {
    const float4 v = ((const float4*)src)[i];
    ushort4 o;
    o.x = f2bf(v.x); o.y = f2bf(v.y); o.z = f2bf(v.z); o.w = f2bf(v.w);
    ((ushort4*)dst)[i] = o;
  }
}

__global__ void conv_w_k(const float* __restrict__ W, ushort_t* __restrict__ Wbf,
                         ushort_t* __restrict__ Wt) {
  int i = blockIdx.x * blockDim.x + threadIdx.x;
  const int stride = gridDim.x * blockDim.x;
  for (; i < NM * NK; i += stride) {
    const ushort_t v = f2bf(W[i]);
    Wbf[i] = v;
    const int m = i >> 11, k = i & (NK - 1);
    Wt[k * NM + m] = v;
  }
}

__global__ void finalize_k(Ctrl* c, int nextbuf) {
  if (c->flag) return;
  const double nd = c->nd, dd = c->dd;
  c->nd = 0.0; c->dd = 0.0;
  c->last = nextbuf;
  if (nd < dd * 1e-4) c->flag = 1;   // ratio^2 < TOL^2 ; dd==0 -> false (inf/nan path)
}

// if the final bf16 r landed in buffer 0 (pred-region alias), copy it to buffer 1
__global__ void fix_alias_k(const Ctrl* __restrict__ c, const uint4* __restrict__ src,
                            uint4* __restrict__ dst) {
  if (c->last != 0) return;
  int i = blockIdx.x * blockDim.x + threadIdx.x;
  const int stride = gridDim.x * blockDim.x;
  const int n = (NB * NK * 2) / 16;
  for (; i < n; i += stride) dst[i] = src[i];
}

extern "C" void kernel_launch(void* const* d_in, const int* in_sizes, int n_in,
                              void* d_out, int out_size, void* d_ws, size_t ws_size,
                              hipStream_t stream) {
  (void)in_sizes; (void)n_in; (void)out_size; (void)ws_size;
  const float* img = (const float*)d_in[0];   // [8192][1024] f32
  const float* W   = (const float*)d_in[1];   // [1024][2048] f32, cols unit-norm

  float* out     = (float*)d_out;
  float* Rst     = out;                        // r state f32 [8192][2048]
  float* predout = out + (size_t)NB * NK;      // pred f32 [8192][1024]
  ushort_t* rbuf0 = (ushort_t*)predout;        // bf16 r ping buffer (aliases pred region)

  char* ws = (char*)d_ws;
  float*    G0    = (float*)(ws + 0);              // 67,108,864 B
  ushort_t* Abf   = (ushort_t*)(ws + 67108864);    //  8,388,608 B (W^T W bf16)
  ushort_t* rbuf1 = (ushort_t*)(ws + 75497472);    // 33,554,432 B
  ushort_t* imgbf = rbuf1;                         // aliased: dead before rbuf1 first write
  ushort_t* Wbf   = (ushort_t*)(ws + 109051904);   //  4,194,304 B
  ushort_t* Wt    = (ushort_t*)(ws + 113246208);   //  4,194,304 B (W^T bf16)
  Ctrl*     ctrl  = (Ctrl*)(ws + 117440512);

  // zero r state + rbuf0 (pred region) and control block
  (void)hipMemsetAsync(d_out, 0, (size_t)100663296, stream);
  (void)hipMemsetAsync(ctrl, 0, 256, stream);

  conv_img_k<<<2048, 256, 0, stream>>>(img, imgbf);
  conv_w_k<<<2048, 256, 0, stream>>>(W, Wbf, Wt);

  // A = W^T W  (2048x2048, KK=1024): Aop = Wt rows, Bop^T = Wt rows (symmetric)
  gemm_bt<0><<<256, 256, 0, stream>>>(Wt, Wt, NM, 16, NK,
                                      nullptr, Abf, nullptr, nullptr, nullptr, ctrl);
  // G0 = img @ W  (8192x2048, KK=1024): Aop = imgbf rows, Bop = Wt rows
  gemm_bt<1><<<1024, 256, 0, stream>>>(imgbf, Wt, NM, 16, NK,
                                       G0, nullptr, nullptr, nullptr, nullptr, ctrl);

  for (int t = 0; t < MAX_T; ++t) {
    ushort_t* rc = (t & 1) ? rbuf1 : rbuf0;
    ushort_t* rn = (t & 1) ? rbuf0 : rbuf1;
    gemm_bt<2><<<1024, 256, 0, stream>>>(rc, Abf, NK, 16, NK,
                                         nullptr, nullptr, G0, Rst, rn, ctrl);
    finalize_k<<<1, 1, 0, stream>>>(ctrl, (t + 1) & 1);
  }

  fix_alias_k<<<2048, 256, 0, stream>>>(ctrl, (const uint4*)rbuf0, (uint4*)rbuf1);
  // pred = r @ W^T (8192x1024, KK=2048): Aop = rbuf1 (final bf16 r), Bop = Wbf rows
  gemm_bt<1><<<512, 256, 0, stream>>>(rbuf1, Wbf, NK, 8, NM,
                                      predout, nullptr, nullptr, nullptr, nullptr, ctrl);
}

// Round 3
// 186.892 us; speedup vs baseline: 120.0407x; 120.0407x over previous
//
#include <hip/hip_runtime.h>

// ---- problem constants ----
#define NB 8192      // batch rows
#define NM 1024      // image dim
#define NK 2048      // dictionary size

typedef unsigned short ushort_t;
using bf16x8 = __attribute__((ext_vector_type(8))) short;
using f32x4  = __attribute__((ext_vector_type(4))) float;

struct Ctrl { double a; double b; int T; float alpha; };

__device__ __forceinline__ ushort_t f2bf(float f) {
  union { float f; unsigned u; } v; v.f = f;
  unsigned r = (v.u + 0x7FFFu + ((v.u >> 16) & 1u)) >> 16;  // RNE
  return (ushort_t)r;
}

__device__ __forceinline__ void gload_lds16(const void* g, void* l) {
  __builtin_amdgcn_global_load_lds(
      (const __attribute__((address_space(1))) unsigned int*)g,
      (__attribute__((address_space(3))) unsigned int*)l, 16, 0, 0);
}

// C = Aop(row-major [rows][KK]) * Bop^T (Bop row-major [cols][KK]); 128x128 tile,
// BK=64, 4 waves, each wave 64x64 via 4x4 frags of mfma_f32_16x16x32_bf16.
// MODE 0: write f32 C + bf16 C, accumulate f64 sum(C^2) into ctrl->a  (G0 pass)
// MODE 1: write f32 C,           accumulate f64 sum(C^2) into ctrl->b  (P pass)
template<int MODE>
__global__ __launch_bounds__(256)
void gemm_bt(const ushort_t* __restrict__ Aop, const ushort_t* __restrict__ Bop,
             int KK, int njb, int outld,
             float* __restrict__ outf, ushort_t* __restrict__ outbf,
             Ctrl* __restrict__ ctrl)
{
  const int tid = threadIdx.x;
  const int w = tid >> 6, l = tid & 63;
  const int wm = w >> 1, wn = w & 1;
  const int bi = blockIdx.x / njb, bj = blockIdx.x % njb;
  const int i0 = bi * 128, j0 = bj * 128;
  const int l15 = l & 15, l16 = l >> 4;
  const int lr = l >> 3;          // staging row-within-8
  const int lc = (l & 7) * 8;     // staging col (elements)

  __shared__ __align__(128) ushort_t As[128 * 64];
  __shared__ __align__(128) ushort_t Bs[128 * 64];
  __shared__ double red[4];

  f32x4 acc[4][4];
#pragma unroll
  for (int m = 0; m < 4; ++m)
#pragma unroll
    for (int n = 0; n < 4; ++n)
      acc[m][n] = (f32x4){0.f, 0.f, 0.f, 0.f};

  for (int k0 = 0; k0 < KK; k0 += 64) {
#pragma unroll
    for (int c = 0; c < 4; ++c) {
      const int rr = c * 32 + w * 8 + lr;
      const ushort_t* ga = Aop + ((size_t)(i0 + rr) * (size_t)KK + k0 + lc);
      const ushort_t* gb = Bop + ((size_t)(j0 + rr) * (size_t)KK + k0 + lc);
      const int base = w * 512 + c * 2048;  // wave-uniform LDS element base
      gload_lds16(ga, &As[base]);
      gload_lds16(gb, &Bs[base]);
    }
    __syncthreads();
#pragma unroll
    for (int ks = 0; ks < 2; ++ks) {
      bf16x8 af[4], bfr[4];
#pragma unroll
      for (int m = 0; m < 4; ++m)
        af[m] = *(const bf16x8*)&As[(wm * 64 + m * 16 + l15) * 64 + ks * 32 + l16 * 8];
#pragma unroll
      for (int n = 0; n < 4; ++n)
        bfr[n] = *(const bf16x8*)&Bs[(wn * 64 + n * 16 + l15) * 64 + ks * 32 + l16 * 8];
#pragma unroll
      for (int m = 0; m < 4; ++m)
#pragma unroll
        for (int n = 0; n < 4; ++n)
          acc[m][n] = __builtin_amdgcn_mfma_f32_16x16x32_bf16(af[m], bfr[n], acc[m][n], 0, 0, 0);
    }
    __syncthreads();
  }

  // epilogue: C/D layout col = lane&15, row = (lane>>4)*4 + reg
  double sq = 0.0;
#pragma unroll
  for (int m = 0; m < 4; ++m) {
#pragma unroll
    for (int n = 0; n < 4; ++n) {
      const int gr0 = i0 + wm * 64 + m * 16 + l16 * 4;
      const int gc  = j0 + wn * 64 + n * 16 + l15;
#pragma unroll
      for (int q4 = 0; q4 < 4; ++q4) {
        const size_t idx = (size_t)(gr0 + q4) * (size_t)outld + gc;
        const float v = acc[m][n][q4];
        outf[idx] = v;
        if constexpr (MODE == 0) outbf[idx] = f2bf(v);
        sq += (double)v * (double)v;
      }
    }
  }
#pragma unroll
  for (int off = 32; off > 0; off >>= 1) sq += __shfl_down(sq, off, 64);
  if (l == 0) red[w] = sq;
  __syncthreads();
  if (tid == 0) {
    const double tot = red[0] + red[1] + red[2] + red[3];
    if constexpr (MODE == 0) atomicAdd(&ctrl->a, tot);
    else                     atomicAdd(&ctrl->b, tot);
  }
}

__global__ void conv_img_k(const float* __restrict__ src, ushort_t* __restrict__ dst) {
  int i = blockIdx.x * blockDim.x + threadIdx.x;
  const int stride = gridDim.x * blockDim.x;
  const int n4 = (NB * NM) / 4;
  for (; i < n4; i += stride) {
    const float4 v = ((const float4*)src)[i];
    ushort4 o;
    o.x = f2bf(v.x); o.y = f2bf(v.y); o.z = f2bf(v.z); o.w = f2bf(v.w);
    ((ushort4*)dst)[i] = o;
  }
}

__global__ void conv_w_k(const float* __restrict__ W, ushort_t* __restrict__ Wbf,
                         ushort_t* __restrict__ Wt) {
  int i = blockIdx.x * blockDim.x + threadIdx.x;
  const int stride = gridDim.x * blockDim.x;
  for (; i < NM * NK; i += stride) {
    const ushort_t v = f2bf(W[i]);
    Wbf[i] = v;
    const int m = i >> 11, k = i & (NK - 1);
    Wt[k * NM + m] = v;
  }
}

// Scalar recurrence in the Krylov basis {G0, G0*A}:
//   r_t = alpha_t*G0 + beta_t*G0A, alpha_t = t*s, beta_t = -s^2 t(t-1)/2
//   ratio_t^2 = s^2(a - 2*alpha_{t-1}*b) / (alpha_{t-1}^2 a + 2 alpha_{t-1} beta_{t-1} b)
// done when ratio^2 < TOL^2 = 1e-4 (first iter: den=0 -> inf -> not done).
__global__ void solve_k(Ctrl* c) {
  const double s = 0.1 * (2.0 / 8388608.0);
  const double a = c->a, b = c->b;
  int T = 10000;
  for (int t = 1; t <= 10000; ++t) {
    const double ap = (double)(t - 1) * s;
    const double bp = -s * s * (double)(t - 1) * (double)(t - 2) * 0.5;
    const double num = s * s * (a - 2.0 * ap * b);
    const double den = ap * ap * a + 2.0 * ap * bp * b;
    if (den > 0.0 && num < 1e-4 * den) { T = t; break; }
  }
  c->T = T;
  c->alpha = (float)((double)T * s);
}

// r = alpha*G0 (in place, d_out r-region), pred = alpha*P (in place, pred-region)
__global__ void scale_k(const Ctrl* __restrict__ c, float4* __restrict__ r4,
                        float4* __restrict__ p4) {
  const float al = c->alpha;
  const int nr4 = (NB * NK) / 4;      // 4,194,304
  const int np4 = (NB * NM) / 4;      // 2,097,152
  int i = blockIdx.x * blockDim.x + threadIdx.x;
  const int stride = gridDim.x * blockDim.x;
  for (; i < nr4 + np4; i += stride) {
    if (i < nr4) {
      float4 v = r4[i];
      v.x *= al; v.y *= al; v.z *= al; v.w *= al;
      r4[i] = v;
    } else {
      const int j = i - nr4;
      float4 v = p4[j];
      v.x *= al; v.y *= al; v.z *= al; v.w *= al;
      p4[j] = v;
    }
  }
}

extern "C" void kernel_launch(void* const* d_in, const int* in_sizes, int n_in,
                              void* d_out, int out_size, void* d_ws, size_t ws_size,
                              hipStream_t stream) {
  (void)in_sizes; (void)n_in; (void)out_size; (void)ws_size;
  const float* img = (const float*)d_in[0];   // [8192][1024] f32
  const float* W   = (const float*)d_in[1];   // [1024][2048] f32, cols unit-norm

  float* Rr = (float*)d_out;                   // G0 -> r, f32 [8192][2048]
  float* Pp = Rr + (size_t)NB * NK;            // P -> pred, f32 [8192][1024]

  char* ws = (char*)d_ws;
  ushort_t* G0bf  = (ushort_t*)(ws + 0);          // 33,554,432 B
  ushort_t* imgbf = (ushort_t*)(ws + 33554432);   // 16,777,216 B
  ushort_t* Wt    = (ushort_t*)(ws + 50331648);   //  4,194,304 B  [2048][1024]
  ushort_t* Wbf   = (ushort_t*)(ws + 54525952);   //  4,194,304 B  [1024][2048]
  Ctrl*     ctrl  = (Ctrl*)(ws + 58720256);

  (void)hipMemsetAsync(ctrl, 0, sizeof(Ctrl), stream);

  conv_img_k<<<2048, 256, 0, stream>>>(img, imgbf);
  conv_w_k<<<2048, 256, 0, stream>>>(W, Wbf, Wt);

  // G0 = img @ W : [8192x2048], KK=1024. A=imgbf rows, B^T = Wt rows.
  // writes G0 f32 into d_out r-region + G0bf, reduces a = ||G0||^2
  gemm_bt<0><<<1024, 256, 0, stream>>>(imgbf, Wt, NM, 16, NK,
                                       Rr, G0bf, ctrl);
  // P = G0 @ W^T : [8192x1024], KK=2048. A=G0bf rows, B^T = Wbf rows.
  // writes P f32 into d_out pred-region, reduces b = ||P||^2
  gemm_bt<1><<<512, 256, 0, stream>>>(G0bf, Wbf, NK, 8, NM,
                                      Pp, nullptr, ctrl);

  solve_k<<<1, 1, 0, stream>>>(ctrl);
  scale_k<<<2048, 256, 0, stream>>>(ctrl, (float4*)Rr, (float4*)Pp);
}